// Round 4
// baseline (145.597 us; speedup 1.0000x reference)
//
#include <hip/hip_runtime.h>
#include <hip/hip_bf16.h>

typedef __bf16 bf16x8 __attribute__((ext_vector_type(8)));
typedef short  s16x4  __attribute__((ext_vector_type(4)));
typedef float  f32x4  __attribute__((ext_vector_type(4)));
typedef unsigned short u16x8 __attribute__((ext_vector_type(8)));
typedef unsigned short u16x4 __attribute__((ext_vector_type(4)));

// ---------- helpers ----------

__device__ __forceinline__ unsigned short f2bf(float f) {
  return __builtin_bit_cast(unsigned short, (__bf16)f);  // RNE via v_cvt
}

__device__ __forceinline__ bf16x8 ld8(const unsigned short* p) {
  return __builtin_bit_cast(bf16x8, *reinterpret_cast<const u16x8*>(p));
}

// async global->LDS, 16B per lane. lds base must be wave-uniform (HW adds lane*16).
__device__ __forceinline__ void gload16(const unsigned short* src, unsigned short* lds) {
  __builtin_amdgcn_global_load_lds(
      (const __attribute__((address_space(1))) unsigned int*)src,
      (__attribute__((address_space(3))) unsigned int*)lds,
      16, 0, 0);
}

// ---------- input conversion: f32 -> bf16 ----------

__global__ __launch_bounds__(256) void cvt_inputs(
    const float* __restrict__ x, const float* __restrict__ Wq,
    const float* __restrict__ Wk, const float* __restrict__ Wv,
    const float* __restrict__ Wo,
    unsigned short* __restrict__ xb, unsigned short* __restrict__ wb) {
  const int NXC = 4194304 / 8;
  const int NWC = 1048576 / 8;   // 131072 = 2^17
  const int total = NXC + 4 * NWC;
  for (int cid = blockIdx.x * 256 + threadIdx.x; cid < total; cid += gridDim.x * 256) {
    const float* s; unsigned short* d; int off;
    if (cid < NXC) { s = x; d = xb; off = cid * 8; }
    else {
      const int c2 = cid - NXC; const int w = c2 >> 17; const int o2 = c2 & (NWC - 1);
      s = (w == 0) ? Wq : (w == 1) ? Wk : (w == 2) ? Wv : Wo;
      d = wb + (size_t)w * 1048576;
      off = o2 * 8;
    }
    const f32x4 a  = *reinterpret_cast<const f32x4*>(s + off);
    const f32x4 b2 = *reinterpret_cast<const f32x4*>(s + off + 4);
    u16x8 o;
#pragma unroll
    for (int j = 0; j < 4; ++j) { o[j] = f2bf(a[j]); o[j + 4] = f2bf(b2[j]); }
    *reinterpret_cast<u16x8*>(d + off) = o;
  }
}

// ---------- GEMM: C[m,n] = sum_k A[m,k] * W[n,k]  (NT, bf16 in, f32 acc) ----------
// M=4096, N=1024, K=1024. 128x128 tile, BK=32, 256 threads (2x2 waves of 64x64).
// mode 0: C float32 row-major (M x 1024)
// mode 1: C bf16 -> qk layout  [(b*16+h)*2048 + s]*64 + d
// mode 2: C bf16 -> v-transposed [(b*16+h)*64 + d]*2048 + s

__device__ __forceinline__ void gemm_body(const unsigned short* __restrict__ A,
                                          const unsigned short* __restrict__ W,
                                          void* __restrict__ Cv, int mode) {
  __shared__ unsigned short As[2][128 * 32];
  __shared__ unsigned short Bs[2][128 * 32];
  const int tid  = threadIdx.x;
  const int lane = tid & 63;
  const int g    = lane >> 4;
  const int lo   = lane & 15;
  const int wid  = tid >> 6;
  const int m0   = blockIdx.y * 128;
  const int n0   = blockIdx.x * 128;
  const int wm   = wid >> 1, wn = wid & 1;

  f32x4 acc[4][4] = {};

  auto stage = [&](int buf, int k0) {
#pragma unroll
    for (int i = 0; i < 2; ++i) {
      const int c   = (i * 4 + wid) * 64 + lane;   // 16B chunk id, 512 total
      const int row = c >> 2, cc = c & 3;          // 4 chunks per 64B row (BK=32)
      gload16(A + (size_t)(m0 + row) * 1024 + k0 + cc * 8, &As[buf][(i * 4 + wid) * 512]);
      gload16(W + (size_t)(n0 + row) * 1024 + k0 + cc * 8, &Bs[buf][(i * 4 + wid) * 512]);
    }
  };

  stage(0, 0);
  __syncthreads();
  int cur = 0;
  for (int t = 0; t < 32; ++t) {
    if (t < 31) stage(cur ^ 1, (t + 1) * 32);
    bf16x8 af[4], bvf[4];
#pragma unroll
    for (int mi = 0; mi < 4; ++mi)
      af[mi] = ld8(&As[cur][(wm * 64 + mi * 16 + lo) * 32 + g * 8]);
#pragma unroll
    for (int ni = 0; ni < 4; ++ni)
      bvf[ni] = ld8(&Bs[cur][(wn * 64 + ni * 16 + lo) * 32 + g * 8]);
#pragma unroll
    for (int mi = 0; mi < 4; ++mi)
#pragma unroll
      for (int ni = 0; ni < 4; ++ni)
        acc[mi][ni] = __builtin_amdgcn_mfma_f32_16x16x32_bf16(af[mi], bvf[ni], acc[mi][ni], 0, 0, 0);
    __syncthreads();
    cur ^= 1;
  }

  // epilogue: C/D layout col = lane&15 (n), row = g*4 + r (m)
#pragma unroll
  for (int mi = 0; mi < 4; ++mi) {
#pragma unroll
    for (int ni = 0; ni < 4; ++ni) {
      const int gcol = n0 + wn * 64 + ni * 16 + lo;
#pragma unroll
      for (int r = 0; r < 4; ++r) {
        const int grow = m0 + wm * 64 + mi * 16 + g * 4 + r;
        if (mode == 0) {
          ((float*)Cv)[(size_t)grow * 1024 + gcol] = acc[mi][ni][r];
        } else {
          const unsigned short bv = f2bf(acc[mi][ni][r]);
          const int b = grow >> 11, s = grow & 2047;
          const int h = gcol >> 6, d = gcol & 63;
          if (mode == 1) ((unsigned short*)Cv)[(((size_t)(b * 16 + h)) * 2048 + s) * 64 + d] = bv;
          else           ((unsigned short*)Cv)[(((size_t)(b * 16 + h)) * 64 + d) * 2048 + s] = bv;
        }
      }
    }
  }
}

__global__ __launch_bounds__(256) void gemm_qkv(
    const unsigned short* __restrict__ xb,
    const unsigned short* __restrict__ wb,
    unsigned short* __restrict__ q_s,
    unsigned short* __restrict__ k_s,
    unsigned short* __restrict__ vt_s) {
  const unsigned short* W = wb + (size_t)blockIdx.z * 1048576;
  void* o; int mode;
  if (blockIdx.z == 0)      { o = q_s;  mode = 1; }
  else if (blockIdx.z == 1) { o = k_s;  mode = 1; }
  else                      { o = vt_s; mode = 2; }
  gemm_body(xb, W, o, mode);
}

__global__ __launch_bounds__(256) void gemm_out(
    const unsigned short* __restrict__ a_s,
    const unsigned short* __restrict__ wb,
    float* __restrict__ out) {
  gemm_body(a_s, wb + (size_t)3 * 1048576, out, 0);
}

// ---------- flash attention (causal, 8-wave paired q-tiles, shared KV staging) ----------
// Q,K: (b,h,s,64) bf16 ; Vt: (b,h,64,s) bf16 ; O: (b,s,1024) bf16
// grid: (16, 32 bh), 512 threads = 8 waves. Waves 0-3 own q-tile 31-i (KV range
// 0..31-i), waves 4-7 own q-tile i (KV range 0..i, a SUBSET) -> one shared KV
// staging stream of 32-i tiles per block. Swapped QK^T: S^T = mfma(K, Q).

__global__ __launch_bounds__(512) void attn_fwd(
    const unsigned short* __restrict__ Q,
    const unsigned short* __restrict__ K,
    const unsigned short* __restrict__ Vt,
    unsigned short* __restrict__ O) {
  __shared__ unsigned short Kl[2][64 * 64];   // [key][d], chunk-swizzled
  __shared__ unsigned short Vl[2][64 * 64];   // [d][s],   chunk-swizzled
  const int tid  = threadIdx.x;
  const int lane = tid & 63;
  const int wid  = tid >> 6;      // 0..7
  const int grp  = wid >> 2;      // 0: big tile, 1: small tile
  const int wq   = wid & 3;
  const int g    = lane >> 4;
  const int lo   = lane & 15;
  const int bh   = blockIdx.y;
  const int b    = bh >> 4, h = bh & 15;
  const int bi   = blockIdx.x;    // 0..15
  const int qt   = grp ? bi : 31 - bi;
  const int myNt = qt + 1;
  const int ntMax= 32 - bi;       // = max over both groups

  const unsigned short* Qb = Q  + (size_t)bh * 2048 * 64;
  const unsigned short* Kb = K  + (size_t)bh * 2048 * 64;
  const unsigned short* Vb = Vt + (size_t)bh * 64 * 2048;
  const float SC = 0.125f * 1.4426950408889634f;  // scale * log2(e): exp2 domain

  const int qw0 = qt * 64 + wq * 16;

  // Q fragments (B operand of swapped QK^T), pre-scaled by SC
  bf16x8 qf[2];
#pragma unroll
  for (int ks = 0; ks < 2; ++ks) {
    bf16x8 tq = ld8(Qb + (size_t)(qw0 + lo) * 64 + ks * 32 + g * 8);
#pragma unroll
    for (int j = 0; j < 8; ++j) tq[j] = (__bf16)((float)tq[j] * SC);
    qf[ks] = tq;
  }

  f32x4 oacc[4] = {};
  float m = -INFINITY, l = 0.f;

  // 512 threads stage one 64x64 K tile + one 64x64 V tile (16 KB): 1 chunk each.
  auto stage = [&](int buf, int t) {
    const int c   = tid;                 // chunk 0..511
    const int row = c >> 3, cc = c & 7;  // 8 chunks per 128B row
    const int scc = cc ^ (row & 7);      // pre-swizzled source (m173)
    gload16(Kb + (size_t)(t * 64 + row) * 64 + scc * 8, &Kl[buf][wid * 512]);
    gload16(Vb + (size_t)row * 2048 + t * 64 + scc * 8, &Vl[buf][wid * 512]);
  };

  stage(0, 0);
  __syncthreads();
  int cur = 0;

  for (int t = 0; t < ntMax; ++t) {
    if (t + 1 < ntMax) stage(cur ^ 1, t + 1);

    if (t < myNt) {
      // S^T[key][q], 4 key-tiles of 16 (already scaled via Q)
      f32x4 sv[4];
      __builtin_amdgcn_s_setprio(1);
#pragma unroll
      for (int kt = 0; kt < 4; ++kt) {
        f32x4 a = {};
#pragma unroll
        for (int ks = 0; ks < 2; ++ks) {
          const int key = kt * 16 + lo;
          const int ck  = ks * 4 + g;
          bf16x8 kf = ld8(&Kl[cur][key * 64 + (ck ^ (key & 7)) * 8]);
          a = __builtin_amdgcn_mfma_f32_16x16x32_bf16(kf, qf[ks], a, 0, 0, 0);
        }
        sv[kt] = a;
      }
      __builtin_amdgcn_s_setprio(0);

      // causal mask (last tile only) + tile max
      const bool lastt = (t == myNt - 1);
      float tmax = -INFINITY;
#pragma unroll
      for (int kt = 0; kt < 4; ++kt)
#pragma unroll
        for (int r = 0; r < 4; ++r) {
          float v = sv[kt][r];
          if (lastt) {
            const int key = t * 64 + kt * 16 + g * 4 + r;
            if (key > qw0 + lo) v = -INFINITY;
          }
          sv[kt][r] = v;
          tmax = fmaxf(tmax, v);
        }
      tmax = fmaxf(tmax, __shfl_xor(tmax, 16));
      tmax = fmaxf(tmax, __shfl_xor(tmax, 32));

      // defer-max (T13): only rescale when running max grew by > 8 (log2 domain)
      if (!__all(tmax <= m + 8.f)) {
        const float mn   = fmaxf(m, tmax);
        const float corr = exp2f(m - mn);
        l *= corr;
#pragma unroll
        for (int dt = 0; dt < 4; ++dt)
#pragma unroll
          for (int r = 0; r < 4; ++r) oacc[dt][r] *= corr;
        m = mn;
      }

      float ps = 0.f;
      s16x4 pb[4];
#pragma unroll
      for (int kt = 0; kt < 4; ++kt)
#pragma unroll
        for (int r = 0; r < 4; ++r) {
          const float p = exp2f(sv[kt][r] - m);   // bounded by 2^8 when deferred
          ps += p;
          pb[kt][r] = (short)f2bf(p);
        }
      ps += __shfl_xor(ps, 16);
      ps += __shfl_xor(ps, 32);
      l += ps;

      // PV: O^T[d][q] += sum_key Vt[d][key] * P^T[key][q]  (16x16x16, k = g*4+j)
      __builtin_amdgcn_s_setprio(1);
#pragma unroll
      for (int dt = 0; dt < 4; ++dt) {
        const int dl = dt * 16 + lo;
#pragma unroll
        for (int kt = 0; kt < 4; ++kt) {
          const int ck  = 2 * kt + (g >> 1);
          const int off = dl * 64 + ((ck ^ (dl & 7)) * 8) + (g & 1) * 4;
          s16x4 vf = *reinterpret_cast<const s16x4*>(&Vl[cur][off]);
          oacc[dt] = __builtin_amdgcn_mfma_f32_16x16x16bf16_1k(vf, pb[kt], oacc[dt], 0, 0, 0);
        }
      }
      __builtin_amdgcn_s_setprio(0);
    }

    __syncthreads();
    cur ^= 1;
  }

  // epilogue: lane's q = qw0+lo; oacc[dt] rows = d = dt*16 + g*4 + r  (bf16 out)
  const float inv = 1.f / l;
  const int s = qw0 + lo;
#pragma unroll
  for (int dt = 0; dt < 4; ++dt) {
    u16x4 pk;
#pragma unroll
    for (int r = 0; r < 4; ++r) pk[r] = f2bf(oacc[dt][r] * inv);
    *reinterpret_cast<u16x4*>(&O[((size_t)(b * 2048 + s)) * 1024 + h * 64 + dt * 16 + g * 4]) = pk;
  }
}

// ---------- launch ----------

extern "C" void kernel_launch(void* const* d_in, const int* in_sizes, int n_in,
                              void* d_out, int out_size, void* d_ws, size_t ws_size,
                              hipStream_t stream) {
  const float* x  = (const float*)d_in[0];
  const float* Wq = (const float*)d_in[1];
  const float* Wk = (const float*)d_in[2];
  const float* Wv = (const float*)d_in[3];
  const float* Wo = (const float*)d_in[4];
  float* out = (float*)d_out;

  char* ws = (char*)d_ws;
  const size_t MiB = 1024 * 1024;
  unsigned short* x_bf = (unsigned short*)(ws);              // 8 MiB (aliased by a_s)
  unsigned short* a_s  = (unsigned short*)(ws);              // 8 MiB bf16 attn out
  unsigned short* w_bf = (unsigned short*)(ws + 8  * MiB);   // 4 x 2 MiB
  unsigned short* q_s  = (unsigned short*)(ws + 16 * MiB);   // 8 MiB
  unsigned short* k_s  = (unsigned short*)(ws + 24 * MiB);   // 8 MiB
  unsigned short* vt_s = (unsigned short*)(ws + 32 * MiB);   // 8 MiB

  cvt_inputs<<<2048, dim3(256), 0, stream>>>(x, Wq, Wk, Wv, Wo, x_bf, w_bf);
  gemm_qkv<<<dim3(8, 32, 3), dim3(256), 0, stream>>>(x_bf, w_bf, q_s, k_s, vt_s);
  attn_fwd<<<dim3(16, 32, 1), dim3(512), 0, stream>>>(q_s, k_s, vt_s, a_s);
  gemm_out<<<dim3(8, 32, 1), dim3(256), 0, stream>>>(a_s, w_bf, out);
}

// Round 6
// 135.702 us; speedup vs baseline: 1.0729x; 1.0729x over previous
//
#include <hip/hip_runtime.h>
#include <hip/hip_bf16.h>

typedef __bf16 bf16x8 __attribute__((ext_vector_type(8)));
typedef short  s16x4  __attribute__((ext_vector_type(4)));
typedef float  f32x4  __attribute__((ext_vector_type(4)));
typedef unsigned short u16x8 __attribute__((ext_vector_type(8)));
typedef unsigned short u16x4 __attribute__((ext_vector_type(4)));

// ---------- helpers ----------

__device__ __forceinline__ unsigned short f2bf(float f) {
  return __builtin_bit_cast(unsigned short, (__bf16)f);  // RNE via v_cvt
}

__device__ __forceinline__ bf16x8 ld8(const unsigned short* p) {
  return __builtin_bit_cast(bf16x8, *reinterpret_cast<const u16x8*>(p));
}

// async global->LDS, 16B per lane. lds base must be wave-uniform (HW adds lane*16).
__device__ __forceinline__ void gload16(const unsigned short* src, unsigned short* lds) {
  __builtin_amdgcn_global_load_lds(
      (const __attribute__((address_space(1))) unsigned int*)src,
      (__attribute__((address_space(3))) unsigned int*)lds,
      16, 0, 0);
}

// ---------- input conversion: f32 -> bf16 ----------

__global__ __launch_bounds__(256) void cvt_inputs(
    const float* __restrict__ x, const float* __restrict__ Wq,
    const float* __restrict__ Wk, const float* __restrict__ Wv,
    const float* __restrict__ Wo,
    unsigned short* __restrict__ xb, unsigned short* __restrict__ wb) {
  const int NXC = 4194304 / 8;
  const int NWC = 1048576 / 8;   // 131072 = 2^17
  const int total = NXC + 4 * NWC;
  for (int cid = blockIdx.x * 256 + threadIdx.x; cid < total; cid += gridDim.x * 256) {
    const float* s; unsigned short* d; int off;
    if (cid < NXC) { s = x; d = xb; off = cid * 8; }
    else {
      const int c2 = cid - NXC; const int w = c2 >> 17; const int o2 = c2 & (NWC - 1);
      s = (w == 0) ? Wq : (w == 1) ? Wk : (w == 2) ? Wv : Wo;
      d = wb + (size_t)w * 1048576;
      off = o2 * 8;
    }
    const f32x4 a  = *reinterpret_cast<const f32x4*>(s + off);
    const f32x4 b2 = *reinterpret_cast<const f32x4*>(s + off + 4);
    u16x8 o;
#pragma unroll
    for (int j = 0; j < 4; ++j) { o[j] = f2bf(a[j]); o[j + 4] = f2bf(b2[j]); }
    *reinterpret_cast<u16x8*>(d + off) = o;
  }
}

// ---------- GEMM: C[m,n] = sum_k A[m,k] * W[n,k]  (NT, bf16 in, f32 acc) ----------
// BM x 128 tile, BK=32, 256 threads, 2x2 waves (wave m-tile = BM/2 rows).
// FM = (BM/2)/16 = BM/32 m-frags per wave (16 rows each).  [round-5 bug: BM/64
// covered only half the rows -> stale poison in half of Q/K/V]
// mode 0: C float32 row-major (M x 1024)
// mode 1: C bf16 -> qk layout  [(b*16+h)*2048 + s]*64 + d
// mode 2: C bf16 -> v-transposed [(b*16+h)*64 + d]*2048 + s

template<int BM>
__device__ __forceinline__ void gemm_body(const unsigned short* __restrict__ A,
                                          const unsigned short* __restrict__ W,
                                          void* __restrict__ Cv, int mode) {
  constexpr int FM  = BM / 32;    // m-frags per wave (wave tile BM/2, 16 rows/frag)
  constexpr int WTM = BM / 2;     // wave m-tile
  __shared__ unsigned short As[2][BM * 32];
  __shared__ unsigned short Bs[2][128 * 32];
  const int tid  = threadIdx.x;
  const int lane = tid & 63;
  const int g    = lane >> 4;
  const int lo   = lane & 15;
  const int wid  = tid >> 6;
  const int m0   = blockIdx.y * BM;
  const int n0   = blockIdx.x * 128;
  const int wm   = wid >> 1, wn = wid & 1;

  f32x4 acc[FM][4] = {};

  auto stage = [&](int buf, int k0) {
#pragma unroll
    for (int i = 0; i < BM / 64; ++i) {          // A: BM*4 chunks of 16B
      const int c   = (i * 4 + wid) * 64 + lane;
      const int row = c >> 2, cc = c & 3;        // 4 chunks per 64B row (BK=32)
      gload16(A + (size_t)(m0 + row) * 1024 + k0 + cc * 8, &As[buf][(i * 4 + wid) * 512]);
    }
#pragma unroll
    for (int i = 0; i < 2; ++i) {                // B: 512 chunks
      const int c   = (i * 4 + wid) * 64 + lane;
      const int row = c >> 2, cc = c & 3;
      gload16(W + (size_t)(n0 + row) * 1024 + k0 + cc * 8, &Bs[buf][(i * 4 + wid) * 512]);
    }
  };

  stage(0, 0);
  __syncthreads();
  int cur = 0;
  for (int t = 0; t < 32; ++t) {
    if (t < 31) stage(cur ^ 1, (t + 1) * 32);
    bf16x8 af[FM], bvf[4];
#pragma unroll
    for (int mi = 0; mi < FM; ++mi)
      af[mi] = ld8(&As[cur][(wm * WTM + mi * 16 + lo) * 32 + g * 8]);
#pragma unroll
    for (int ni = 0; ni < 4; ++ni)
      bvf[ni] = ld8(&Bs[cur][(wn * 64 + ni * 16 + lo) * 32 + g * 8]);
#pragma unroll
    for (int mi = 0; mi < FM; ++mi)
#pragma unroll
      for (int ni = 0; ni < 4; ++ni)
        acc[mi][ni] = __builtin_amdgcn_mfma_f32_16x16x32_bf16(af[mi], bvf[ni], acc[mi][ni], 0, 0, 0);
    __syncthreads();
    cur ^= 1;
  }

  // epilogue: C/D layout col = lane&15 (n), row = g*4 + r (m)
#pragma unroll
  for (int mi = 0; mi < FM; ++mi) {
#pragma unroll
    for (int ni = 0; ni < 4; ++ni) {
      const int gcol = n0 + wn * 64 + ni * 16 + lo;
#pragma unroll
      for (int r = 0; r < 4; ++r) {
        const int grow = m0 + wm * WTM + mi * 16 + g * 4 + r;
        if (mode == 0) {
          ((float*)Cv)[(size_t)grow * 1024 + gcol] = acc[mi][ni][r];
        } else {
          const unsigned short bv = f2bf(acc[mi][ni][r]);
          const int b = grow >> 11, s = grow & 2047;
          const int h = gcol >> 6, d = gcol & 63;
          if (mode == 1) ((unsigned short*)Cv)[(((size_t)(b * 16 + h)) * 2048 + s) * 64 + d] = bv;
          else           ((unsigned short*)Cv)[(((size_t)(b * 16 + h)) * 64 + d) * 2048 + s] = bv;
        }
      }
    }
  }
}

__global__ __launch_bounds__(256) void gemm_qkv(
    const unsigned short* __restrict__ xb,
    const unsigned short* __restrict__ wb,
    unsigned short* __restrict__ q_s,
    unsigned short* __restrict__ k_s,
    unsigned short* __restrict__ vt_s) {
  const unsigned short* W = wb + (size_t)blockIdx.z * 1048576;
  void* o; int mode;
  if (blockIdx.z == 0)      { o = q_s;  mode = 1; }
  else if (blockIdx.z == 1) { o = k_s;  mode = 1; }
  else                      { o = vt_s; mode = 2; }
  gemm_body<128>(xb, W, o, mode);
}

__global__ __launch_bounds__(256) void gemm_out(
    const unsigned short* __restrict__ a_s,
    const unsigned short* __restrict__ wb,
    float* __restrict__ out) {
  gemm_body<64>(a_s, wb + (size_t)3 * 1048576, out, 0);
}

// ---------- flash attention (causal, 8-wave paired q-tiles, shared KV staging) ----------
// Q,K: (b,h,s,64) bf16 ; Vt: (b,h,64,s) bf16 ; O: (b,s,1024) bf16
// grid: (16, 32 bh), 512 threads = 8 waves. Waves 0-3 own q-tile 31-i, waves 4-7
// own q-tile i (KV range subset) -> one shared KV staging stream of 32-i tiles.
// Swapped QK^T: S^T = mfma(K, Q). Steady-state rounds have ZERO cross-lane ops:
// per-lane partial l (corr is row-uniform), defer-max check on lane-local max
// (the __all ballot is exactly as conservative as the row-reduced check).

__global__ __launch_bounds__(512) void attn_fwd(
    const unsigned short* __restrict__ Q,
    const unsigned short* __restrict__ K,
    const unsigned short* __restrict__ Vt,
    unsigned short* __restrict__ O) {
  __shared__ unsigned short Kl[2][64 * 64];   // [key][d], chunk-swizzled
  __shared__ unsigned short Vl[2][64 * 64];   // [d][s],   chunk-swizzled
  const int tid  = threadIdx.x;
  const int lane = tid & 63;
  const int wid  = tid >> 6;      // 0..7
  const int grp  = wid >> 2;      // 0: big tile, 1: small tile
  const int wq   = wid & 3;
  const int g    = lane >> 4;
  const int lo   = lane & 15;
  const int bh   = blockIdx.y;
  const int b    = bh >> 4, h = bh & 15;
  const int bi   = blockIdx.x;    // 0..15
  const int qt   = grp ? bi : 31 - bi;
  const int myNt = qt + 1;
  const int ntMax= 32 - bi;       // = max over both groups

  const unsigned short* Qb = Q  + (size_t)bh * 2048 * 64;
  const unsigned short* Kb = K  + (size_t)bh * 2048 * 64;
  const unsigned short* Vb = Vt + (size_t)bh * 64 * 2048;
  const float SC = 0.125f * 1.4426950408889634f;  // scale * log2(e): exp2 domain

  const int qw0 = qt * 64 + wq * 16;

  // Q fragments (B operand of swapped QK^T), pre-scaled by SC
  bf16x8 qf[2];
#pragma unroll
  for (int ks = 0; ks < 2; ++ks) {
    bf16x8 tq = ld8(Qb + (size_t)(qw0 + lo) * 64 + ks * 32 + g * 8);
#pragma unroll
    for (int j = 0; j < 8; ++j) tq[j] = (__bf16)((float)tq[j] * SC);
    qf[ks] = tq;
  }

  f32x4 oacc[4] = {};
  float m = -INFINITY;
  float l = 0.f;                  // PER-LANE partial; reduced once in epilogue

  // 512 threads stage one 64x64 K tile + one 64x64 V tile (16 KB): 1 chunk each.
  auto stage = [&](int buf, int t) {
    const int c   = tid;                 // chunk 0..511
    const int row = c >> 3, cc = c & 7;  // 8 chunks per 128B row
    const int scc = cc ^ (row & 7);      // pre-swizzled source (m173)
    gload16(Kb + (size_t)(t * 64 + row) * 64 + scc * 8, &Kl[buf][wid * 512]);
    gload16(Vb + (size_t)row * 2048 + t * 64 + scc * 8, &Vl[buf][wid * 512]);
  };

  stage(0, 0);
  __syncthreads();
  int cur = 0;

  for (int t = 0; t < ntMax; ++t) {
    if (t + 1 < ntMax) stage(cur ^ 1, t + 1);

    if (t < myNt) {
      // S^T[key][q], 4 key-tiles of 16 (already scaled via Q)
      f32x4 sv[4];
      __builtin_amdgcn_s_setprio(1);
#pragma unroll
      for (int kt = 0; kt < 4; ++kt) {
        f32x4 a = {};
#pragma unroll
        for (int ks = 0; ks < 2; ++ks) {
          const int key = kt * 16 + lo;
          const int ck  = ks * 4 + g;
          bf16x8 kf = ld8(&Kl[cur][key * 64 + (ck ^ (key & 7)) * 8]);
          a = __builtin_amdgcn_mfma_f32_16x16x32_bf16(kf, qf[ks], a, 0, 0, 0);
        }
        sv[kt] = a;
      }
      __builtin_amdgcn_s_setprio(0);

      // causal mask (last tile only) + lane-local tile max (NO cross-lane ops)
      const bool lastt = (t == myNt - 1);
      float tmax = -INFINITY;
#pragma unroll
      for (int kt = 0; kt < 4; ++kt)
#pragma unroll
        for (int r = 0; r < 4; ++r) {
          float v = sv[kt][r];
          if (lastt) {
            const int key = t * 64 + kt * 16 + g * 4 + r;
            if (key > qw0 + lo) v = -INFINITY;
          }
          sv[kt][r] = v;
          tmax = fmaxf(tmax, v);
        }

      // defer-max (T13): rescale only when some lane's local max grew past m+8.
      // Branch is wave-uniform; row-max shfls only happen here (rare).
      if (!__all(tmax <= m + 8.f)) {
        float rmax = fmaxf(tmax, __shfl_xor(tmax, 16));
        rmax = fmaxf(rmax, __shfl_xor(rmax, 32));
        const float mn   = fmaxf(m, rmax);
        const float corr = exp2f(m - mn);
        l *= corr;
#pragma unroll
        for (int dt = 0; dt < 4; ++dt)
#pragma unroll
          for (int r = 0; r < 4; ++r) oacc[dt][r] *= corr;
        m = mn;
      }

      // P = exp2(S - m), bounded by 2^8; per-lane partial l accumulation
      s16x4 pb[4];
      float ps = 0.f;
#pragma unroll
      for (int kt = 0; kt < 4; ++kt)
#pragma unroll
        for (int r = 0; r < 4; ++r) {
          const float p = exp2f(sv[kt][r] - m);
          ps += p;
          pb[kt][r] = (short)f2bf(p);
        }
      l += ps;

      // PV: O^T[d][q] += sum_key Vt[d][key] * P^T[key][q]  (16x16x16, k = g*4+j)
      __builtin_amdgcn_s_setprio(1);
#pragma unroll
      for (int dt = 0; dt < 4; ++dt) {
        const int dl = dt * 16 + lo;
#pragma unroll
        for (int kt = 0; kt < 4; ++kt) {
          const int ck  = 2 * kt + (g >> 1);
          const int off = dl * 64 + ((ck ^ (dl & 7)) * 8) + (g & 1) * 4;
          s16x4 vf = *reinterpret_cast<const s16x4*>(&Vl[cur][off]);
          oacc[dt] = __builtin_amdgcn_mfma_f32_16x16x16bf16_1k(vf, pb[kt], oacc[dt], 0, 0, 0);
        }
      }
      __builtin_amdgcn_s_setprio(0);
    }

    __syncthreads();
    cur ^= 1;
  }

  // epilogue: reduce per-lane l across the row's 4 g-lanes (once per q-tile)
  l += __shfl_xor(l, 16);
  l += __shfl_xor(l, 32);
  const float inv = 1.f / l;
  const int s = qw0 + lo;
#pragma unroll
  for (int dt = 0; dt < 4; ++dt) {
    u16x4 pk;
#pragma unroll
    for (int r = 0; r < 4; ++r) pk[r] = f2bf(oacc[dt][r] * inv);
    *reinterpret_cast<u16x4*>(&O[((size_t)(b * 2048 + s)) * 1024 + h * 64 + dt * 16 + g * 4]) = pk;
  }
}

// ---------- launch ----------

extern "C" void kernel_launch(void* const* d_in, const int* in_sizes, int n_in,
                              void* d_out, int out_size, void* d_ws, size_t ws_size,
                              hipStream_t stream) {
  const float* x  = (const float*)d_in[0];
  const float* Wq = (const float*)d_in[1];
  const float* Wk = (const float*)d_in[2];
  const float* Wv = (const float*)d_in[3];
  const float* Wo = (const float*)d_in[4];
  float* out = (float*)d_out;

  char* ws = (char*)d_ws;
  const size_t MiB = 1024 * 1024;
  unsigned short* x_bf = (unsigned short*)(ws);              // 8 MiB (aliased by a_s)
  unsigned short* a_s  = (unsigned short*)(ws);              // 8 MiB bf16 attn out
  unsigned short* w_bf = (unsigned short*)(ws + 8  * MiB);   // 4 x 2 MiB
  unsigned short* q_s  = (unsigned short*)(ws + 16 * MiB);   // 8 MiB
  unsigned short* k_s  = (unsigned short*)(ws + 24 * MiB);   // 8 MiB
  unsigned short* vt_s = (unsigned short*)(ws + 32 * MiB);   // 8 MiB

  cvt_inputs<<<2048, dim3(256), 0, stream>>>(x, Wq, Wk, Wv, Wo, x_bf, w_bf);
  gemm_qkv<<<dim3(8, 32, 3), dim3(256), 0, stream>>>(x_bf, w_bf, q_s, k_s, vt_s);
  attn_fwd<<<dim3(16, 32, 1), dim3(512), 0, stream>>>(q_s, k_s, vt_s, a_s);
  gemm_out<<<dim3(8, 64, 1), dim3(256), 0, stream>>>(a_s, w_bf, out);
}